// Round 6
// baseline (243.666 us; speedup 1.0000x reference)
//
#include <hip/hip_runtime.h>
#include <hip/hip_bf16.h>

#define IN_D 112
#define OUT_D 111
#define MDIM 16
#define DC 8   // d-outputs streamed per thread

// Lane layout: lane = 4*ci + q. ci = local column (0..15), q = channel quad.
// Wave g covers output columns g*15 .. g*15+14 (16 input columns, waves
// overlap by 1). All global loads/stores are 16 B/lane fully contiguous.
// M is a per-lane pre-permuted 4x4-of-float4 fragment PINNED in VGPRs via an
// empty asm "+v" constraint (round 5: at 64-VGPR budget the compiler
// rematerialized M by reloading 16 float4 from global EVERY k-step, polluting
// vmcnt and serializing the stream pipeline).
// d-streaming with a 3-slot ring: slab d0+k+4 prefetched at step k, consumed
// at step k+3 -> ~6 outstanding 1KB wave-loads.
__device__ __forceinline__ float4 f4add(float4 a, float4 b) {
    return make_float4(a.x + b.x, a.y + b.y, a.z + b.z, a.w + b.w);
}
__device__ __forceinline__ float4 shfl_down4(float4 v) {
    return make_float4(__shfl_down(v.x, 4, 64), __shfl_down(v.y, 4, 64),
                       __shfl_down(v.z, 4, 64), __shfl_down(v.w, 4, 64));
}
__device__ __forceinline__ float4 shfl_xor4(float4 v, int m) {
    return make_float4(__shfl_xor(v.x, m, 64), __shfl_xor(v.y, m, 64),
                       __shfl_xor(v.z, m, 64), __shfl_xor(v.w, m, 64));
}

__global__ __launch_bounds__(256, 4)
void spatial_dual_desc_kernel(const float* __restrict__ x,
                              const float* __restrict__ Mg,
                              float* __restrict__ out) {
    const int lane = threadIdx.x & 63;
    const int wid  = threadIdx.x >> 6;          // 0..3
    const int g    = blockIdx.x * 4 + wid;      // wave slot 0..7
    const int ci   = lane >> 2;                 // 0..15
    const int q    = lane & 3;                  // 0..3
    const int col  = g * 15 + ci;               // candidate output column
    const int c    = (col < IN_D) ? col : (IN_D - 1);
    const int h    = blockIdx.y;
    const int d0   = blockIdx.z * DC;

    // Per-lane permuted M fragment: Mreg[i][m] = quad (q^m) of row (4q+i).
    float4 Mreg[4][4];
#pragma unroll
    for (int i = 0; i < 4; ++i)
#pragma unroll
        for (int m = 0; m < 4; ++m)
            Mreg[i][m] = *(const float4*)(Mg + (4 * q + i) * MDIM + 4 * (q ^ m));
    // Pin M in VGPRs: empty asm makes the values opaque -> no rematerialization.
#pragma unroll
    for (int i = 0; i < 4; ++i)
#pragma unroll
        for (int m = 0; m < 4; ++m)
            asm volatile("" : "+v"(Mreg[i][m].x), "+v"(Mreg[i][m].y),
                              "+v"(Mreg[i][m].z), "+v"(Mreg[i][m].w));

    const size_t row_stride  = (size_t)IN_D * MDIM;          // h step (floats)
    const size_t slab_stride = (size_t)IN_D * row_stride;    // d step (floats)
    const float* bp = x + ((size_t)h * IN_D + c) * MDIM + 4 * q;

    // Prologue: slab d0 -> rs_prev; ring <- slabs d0+1, d0+2, d0+3.
    float4 a0 = *(const float4*)(bp + (size_t)d0 * slab_stride);
    float4 b0 = *(const float4*)(bp + (size_t)d0 * slab_stride + row_stride);
    float4 ring[3][2];
#pragma unroll
    for (int r = 0; r < 3; ++r) {
        const float* p = bp + (size_t)(d0 + 1 + r) * slab_stride;
        ring[r][0] = *(const float4*)p;
        ring[r][1] = *(const float4*)(p + row_stride);
    }

    float4 rs_prev = f4add(a0, b0);

#pragma unroll
    for (int k = 0; k < DC; ++k) {
        const int dcur = d0 + k;
        const int r = k % 3;
        float4 rs_new = f4add(ring[r][0], ring[r][1]);   // slab d0+k+1 row-pair

        // Prefetch slab d0+k+4 into the slot just freed (depth-3 pipeline).
        if (k < DC - 3) {
            int dn = d0 + k + 4;
            if (dn > IN_D - 1) dn = IN_D - 1;
            const float* p = bp + (size_t)dn * slab_stride;
            ring[r][0] = *(const float4*)p;
            ring[r][1] = *(const float4*)(p + row_stride);
        }

        // d-pair, then w-pair (neighbor column = lane+4), per-quad.
        float4 s4 = f4add(rs_prev, rs_new);
        float4 w4 = f4add(s4, shfl_down4(s4));

        // Gather the other 3 quads of the window-sum vector.
        float4 p1 = shfl_xor4(w4, 1);
        float4 p2 = shfl_xor4(w4, 2);
        float4 p3 = shfl_xor4(w4, 3);

        float o[4];
#pragma unroll
        for (int i = 0; i < 4; ++i) {
            float acc;
            acc  = w4.x * Mreg[i][0].x + w4.y * Mreg[i][0].y + w4.z * Mreg[i][0].z + w4.w * Mreg[i][0].w;
            acc += p1.x * Mreg[i][1].x + p1.y * Mreg[i][1].y + p1.z * Mreg[i][1].z + p1.w * Mreg[i][1].w;
            acc += p2.x * Mreg[i][2].x + p2.y * Mreg[i][2].y + p2.z * Mreg[i][2].z + p2.w * Mreg[i][2].w;
            acc += p3.x * Mreg[i][3].x + p3.y * Mreg[i][3].y + p3.z * Mreg[i][3].z + p3.w * Mreg[i][3].w;
            o[i] = acc * 0.125f;
        }

        if (ci < 15 && col < OUT_D && dcur < OUT_D) {
            *(float4*)(out + (((size_t)dcur * OUT_D + h) * OUT_D + col) * MDIM + 4 * q)
                = make_float4(o[0], o[1], o[2], o[3]);
        }
        rs_prev = rs_new;
    }
}

extern "C" void kernel_launch(void* const* d_in, const int* in_sizes, int n_in,
                              void* d_out, int out_size, void* d_ws, size_t ws_size,
                              hipStream_t stream) {
    const float* x = (const float*)d_in[0];   // (112,112,112,16) fp32
    const float* M = (const float*)d_in[1];   // (16,16) fp32
    float* out = (float*)d_out;               // (111^3, 16) fp32

    dim3 block(256, 1, 1);
    dim3 grid(2, OUT_D, (OUT_D + DC - 1) / DC);   // 2 x 111 x 14
    spatial_dual_desc_kernel<<<grid, block, 0, stream>>>(x, M, out);
}

// Round 7
// 164.674 us; speedup vs baseline: 1.4797x; 1.4797x over previous
//
#include <hip/hip_runtime.h>
#include <hip/hip_bf16.h>

#define IN_D 112
#define OUT_D 111
#define MDIM 16
#define DC 8   // d-outputs streamed per thread

// Lane layout: lane = 4*ci + q. ci = local column (0..15), q = channel quad.
// Wave g covers output columns g*15 .. g*15+14 (16 input columns, waves
// overlap by 1). All global loads/stores are 16 B/lane fully contiguous.
//
// M lives in LDS as a per-q pre-permuted fragment:
//   sM4[q*17 + (i*4+m)] = quad (q^m) of row (4q+i)   (float4 entries)
// The +1 pad per q-block puts the 4 distinct broadcast addresses of each
// ds_read_b128 on disjoint bank quads -> conflict-free. Reading M from LDS
// per k-step keeps it off the vmcnt queue (round 4 reloaded M from GLOBAL
// every step, serializing the stream pipeline; round 5's VGPR pin spilled
// to scratch: +150 MB HBM traffic. LDS is the right home.)
__device__ __forceinline__ float4 f4add(float4 a, float4 b) {
    return make_float4(a.x + b.x, a.y + b.y, a.z + b.z, a.w + b.w);
}
__device__ __forceinline__ float4 shfl_down4(float4 v) {
    return make_float4(__shfl_down(v.x, 4, 64), __shfl_down(v.y, 4, 64),
                       __shfl_down(v.z, 4, 64), __shfl_down(v.w, 4, 64));
}
__device__ __forceinline__ float4 shfl_xor4(float4 v, int m) {
    return make_float4(__shfl_xor(v.x, m, 64), __shfl_xor(v.y, m, 64),
                       __shfl_xor(v.z, m, 64), __shfl_xor(v.w, m, 64));
}

__global__ __launch_bounds__(256)
void spatial_dual_desc_kernel(const float* __restrict__ x,
                              const float* __restrict__ Mg,
                              float* __restrict__ out) {
    __shared__ float4 sM4[4 * 17];   // 68 float4 = 1088 B (4 pad slots unused)

    const int tid  = threadIdx.x;
    const int lane = tid & 63;
    const int wid  = tid >> 6;                  // 0..3
    const int g    = blockIdx.x * 4 + wid;      // wave slot 0..7
    const int ci   = lane >> 2;                 // 0..15
    const int q    = lane & 3;                  // 0..3
    const int col  = g * 15 + ci;               // candidate output column
    const int c    = (col < IN_D) ? col : (IN_D - 1);
    const int h    = blockIdx.y;
    const int d0   = blockIdx.z * DC;

    // Fill the permuted M fragment (threads 0..63, one float4 each).
    if (tid < 64) {
        const int fq  = tid >> 4;        // 0..3
        const int idx = tid & 15;        // i*4+m
        const int fi  = idx >> 2;
        const int fm  = idx & 3;
        sM4[fq * 17 + idx] =
            *(const float4*)(Mg + (4 * fq + fi) * MDIM + 4 * (fq ^ fm));
    }
    __syncthreads();

    const float4* Mq = &sM4[q * 17];   // this lane's 16-float4 fragment

    const size_t row_stride  = (size_t)IN_D * MDIM;          // h step (floats)
    const size_t slab_stride = (size_t)IN_D * row_stride;    // d step (floats)
    const float* bp = x + ((size_t)h * IN_D + c) * MDIM + 4 * q;

    // Prologue: slab d0 row pair -> rs_prev; prefetch slabs d0+1, d0+2.
    float4 a0 = *(const float4*)(bp + (size_t)d0 * slab_stride);
    float4 b0 = *(const float4*)(bp + (size_t)d0 * slab_stride + row_stride);
    float4 buf[2][2];
    buf[0][0] = *(const float4*)(bp + (size_t)(d0 + 1) * slab_stride);
    buf[0][1] = *(const float4*)(bp + (size_t)(d0 + 1) * slab_stride + row_stride);
    buf[1][0] = *(const float4*)(bp + (size_t)(d0 + 2) * slab_stride);
    buf[1][1] = *(const float4*)(bp + (size_t)(d0 + 2) * slab_stride + row_stride);

    float4 rs_prev = f4add(a0, b0);

#pragma unroll
    for (int k = 0; k < DC; ++k) {
        const int dcur = d0 + k;
        float4 rs_new = f4add(buf[k & 1][0], buf[k & 1][1]);

        // Prefetch slab dcur+3 into the buffer just freed (depth-2 pipeline).
        if (k < DC - 2) {
            int dn = d0 + k + 3;
            if (dn > IN_D - 1) dn = IN_D - 1;
            const float* p = bp + (size_t)dn * slab_stride;
            buf[k & 1][0] = *(const float4*)p;
            buf[k & 1][1] = *(const float4*)(p + row_stride);
        }

        // d-pair, then w-pair (neighbor column = lane+4), per-quad.
        float4 s4 = f4add(rs_prev, rs_new);
        float4 w4 = f4add(s4, shfl_down4(s4));

        // Gather the other 3 quads of the window-sum vector.
        float4 p1 = shfl_xor4(w4, 1);
        float4 p2 = shfl_xor4(w4, 2);
        float4 p3 = shfl_xor4(w4, 3);

        float o[4];
#pragma unroll
        for (int i = 0; i < 4; ++i) {
            const float4 m0 = Mq[i * 4 + 0];
            const float4 m1 = Mq[i * 4 + 1];
            const float4 m2 = Mq[i * 4 + 2];
            const float4 m3 = Mq[i * 4 + 3];
            float acc;
            acc  = w4.x * m0.x + w4.y * m0.y + w4.z * m0.z + w4.w * m0.w;
            acc += p1.x * m1.x + p1.y * m1.y + p1.z * m1.z + p1.w * m1.w;
            acc += p2.x * m2.x + p2.y * m2.y + p2.z * m2.z + p2.w * m2.w;
            acc += p3.x * m3.x + p3.y * m3.y + p3.z * m3.z + p3.w * m3.w;
            o[i] = acc * 0.125f;
        }

        if (ci < 15 && col < OUT_D && dcur < OUT_D) {
            *(float4*)(out + (((size_t)dcur * OUT_D + h) * OUT_D + col) * MDIM + 4 * q)
                = make_float4(o[0], o[1], o[2], o[3]);
        }
        rs_prev = rs_new;
    }
}

extern "C" void kernel_launch(void* const* d_in, const int* in_sizes, int n_in,
                              void* d_out, int out_size, void* d_ws, size_t ws_size,
                              hipStream_t stream) {
    const float* x = (const float*)d_in[0];   // (112,112,112,16) fp32
    const float* M = (const float*)d_in[1];   // (16,16) fp32
    float* out = (float*)d_out;               // (111^3, 16) fp32

    dim3 block(256, 1, 1);
    dim3 grid(2, OUT_D, (OUT_D + DC - 1) / DC);   // 2 x 111 x 14
    spatial_dual_desc_kernel<<<grid, block, 0, stream>>>(x, M, out);
}